// Round 13
// baseline (151.397 us; speedup 1.0000x reference)
//
#include <hip/hip_runtime.h>
#include <hip/hip_bf16.h>
#include <stdint.h>

#define B_ 8
#define S_ 2048
#define D_ 128
#define QBLK 64
#define KVB 128            // keys per block-iteration (64 per kvh-half)
#define NIT (S_ / KVB)     // 16
#define VST 72             // padded f16 stride for V^T / P tiles (64+8)

typedef _Float16 f16;
typedef f16 f16x8 __attribute__((ext_vector_type(8)));
typedef f16 f16x4 __attribute__((ext_vector_type(4)));
typedef f16 f16x2 __attribute__((ext_vector_type(2)));
typedef float f32x4 __attribute__((ext_vector_type(4)));

// 512 threads = 8 waves: rowgrp = w&3 (16 q-rows), kvh = w>>2 (64-key half of each tile).
// LDS bytes: Klds @0 (2 halves x [64][128] f16, (r&15)<<3 swizzle) 32768
//            Vt @32768 (2 halves x [128 d][VST] f16)               36864
//            Pl @69632 (8 waves x [16][VST] f16)                   18432
//            madd @88064 (128 f32)                                   512  -> 88576
// epilogue overlay (post final barrier): mrg 4x[16][132] f32 @0, mlb @69632
__global__ __launch_bounds__(512, 2) void attn_fwd(const float* __restrict__ Q,
                                                   const float* __restrict__ K,
                                                   const float* __restrict__ V,
                                                   const void* __restrict__ Mp,
                                                   float* __restrict__ O) {
  const int t = threadIdx.x;
  const int bid = blockIdx.x;
  const int b = bid & 7;             // XCD-aware: batch == bid%8 == likely XCD id
  const int q0 = (bid >> 3) * QBLK;
  const int w = t >> 6, l = t & 63, l15 = l & 15, lg = l >> 4;
  const int rowgrp = w & 3, kvh = w >> 2;

  __shared__ alignas(16) char smem[88576];
  f16* Klds   = (f16*)smem;                 // kvh*8192 + swizzled idx
  f16* Vt     = (f16*)(smem + 32768);       // kvh*9216 + d*VST + key
  f16* Pl     = (f16*)(smem + 69632);       // w*1152 + row*VST + key
  float* madd = (float*)(smem + 88064);
  float* mrg  = (float*)smem;
  float* mlb  = (float*)(smem + 69632);

  // ---- mask dtype detection (int32 / uint8-bool / float32), block-uniform ----
  const uint32_t* mw = (const uint32_t*)Mp;
  int oki = 1, okf = 1;
#pragma unroll
  for (int i = 0; i < 4; ++i) {
    uint32_t x = mw[t * 4 + i];
    oki &= (x <= 1u) ? 1 : 0;
    okf &= (x == 0u || x == 0x3f800000u) ? 1 : 0;
  }
  const int alli = __syncthreads_and(oki);
  const int allf = __syncthreads_and(okf);
  const int mode = alli ? 0 : (allf ? 2 : 1);
  const int*     mi32 = (const int*)Mp + b * S_;
  const uint8_t* mu8  = (const uint8_t*)Mp + b * S_;
  const float*   mf32 = (const float*)Mp + b * S_;

  // ---- Q fragments (B-operand of swapped QK): col = l15 = qrow, k = lg*8+j+32kt ----
  f16x8 qf[4];
  {
    const int qrow = q0 + 16 * rowgrp + l15;
    const float* qp = Q + ((size_t)b * S_ + qrow) * D_ + lg * 8;
#pragma unroll
    for (int kt = 0; kt < 4; ++kt) {
      float4 a = *(const float4*)(qp + 32 * kt);
      float4 c = *(const float4*)(qp + 32 * kt + 4);
      qf[kt] = (f16x8){(f16)a.x, (f16)a.y, (f16)a.z, (f16)a.w,
                       (f16)c.x, (f16)c.y, (f16)c.z, (f16)c.w};
    }
  }

  f32x4 acco[8];
#pragma unroll
  for (int dt = 0; dt < 8; ++dt) acco[dt] = (f32x4){0.f, 0.f, 0.f, 0.f};
  float m_r = -1e30f, l_r = 0.f;   // state for qrow = l15 (replicated over 4 lgs)

  // ---- staging geometry: 512 threads stage 128 keys of K, V, mask ----
  const float* Kb = K + (size_t)b * S_ * D_;
  const float* Vb = V + (size_t)b * S_ * D_;
  const int krow = t >> 2;          // K row 0..127
  const int kcol0 = (t & 3) * 32;   // K col base
  const int vc  = (t >> 4) * 4;     // V d base 0..124
  const int vkp = t & 15;           // V key-pair base

  float4 kreg[8], vreg[8];
  float mreg = 0.f;

#define LOADT(KV0)                                                                     \
  {                                                                                    \
    _Pragma("unroll") for (int p = 0; p < 8; ++p)                                      \
      kreg[p] = *(const float4*)(Kb + (size_t)((KV0) + krow) * D_ + kcol0 + 4 * p);    \
    _Pragma("unroll") for (int p = 0; p < 4; ++p) {                                    \
      const int g = 2 * (vkp + 16 * p);                                                \
      const float* vp = Vb + (size_t)((KV0) + g) * D_ + vc;                            \
      vreg[2 * p]     = *(const float4*)vp;                                            \
      vreg[2 * p + 1] = *(const float4*)(vp + D_);                                     \
    }                                                                                  \
    if (t < KVB) {                                                                     \
      const int gk = (KV0) + t;                                                        \
      mreg = (mode == 0) ? (mi32[gk] ? 1.f : 0.f)                                      \
           : (mode == 1) ? (mu8[gk] ? 1.f : 0.f) : mf32[gk];                           \
    }                                                                                  \
  }

  LOADT(0);

  for (int it = 0; it < NIT; ++it) {
    // ---- convert staged regs -> LDS ----
    {
      const int half = krow >> 6, r = krow & 63;
      const int swz = (r & 15) << 3;
#pragma unroll
      for (int p = 0; p < 8; ++p) {
        const int idx = half * 8192 + ((r * 128 + kcol0 + 4 * p) ^ swz);
        float4 kv = kreg[p];
        *(f16x4*)(Klds + idx) = (f16x4){(f16)kv.x, (f16)kv.y, (f16)kv.z, (f16)kv.w};
      }
    }
#pragma unroll
    for (int p = 0; p < 4; ++p) {
      const int g = 2 * (vkp + 16 * p), half = g >> 6, gl = g & 63;
      float4 v0 = vreg[2 * p], v1 = vreg[2 * p + 1];
#pragma unroll
      for (int i = 0; i < 4; ++i)
        *(f16x2*)(Vt + half * 9216 + (vc + i) * VST + gl) =
            (f16x2){(f16)(&v0.x)[i], (f16)(&v1.x)[i]};
    }
    if (t < KVB) madd[t] = (mreg != 0.f) ? -1e30f : 0.f;
    __syncthreads();

    // ---- prefetch next tile (hides under QK/softmax/PV) ----
    if (it + 1 < NIT) LOADT((it + 1) * KVB);

    // ---- swapped QK^T: sacc[nt][r] = S[key = kvh*64 + 16nt+4lg+r][qrow = l15] ----
    f32x4 sacc[4];
#pragma unroll
    for (int nt = 0; nt < 4; ++nt) sacc[nt] = (f32x4){0.f, 0.f, 0.f, 0.f};
    const int swzr = l15 << 3;   // (r&15)<<3 with r = 16nt + l15
#pragma unroll
    for (int nt = 0; nt < 4; ++nt) {
#pragma unroll
      for (int kt = 0; kt < 4; ++kt) {
        const int idx = kvh * 8192 + (((16 * nt + l15) * 128 + 8 * lg + 32 * kt) ^ swzr);
        f16x8 kf = *(const f16x8*)(Klds + idx);
        sacc[nt] = __builtin_amdgcn_mfma_f32_16x16x32_f16(kf, qf[kt], sacc[nt], 0, 0, 0);
      }
    }

    // ---- lane-local softmax over 16 keys (additive mask pre-max; exact) ----
    f32x4 sm[4];
#pragma unroll
    for (int nt = 0; nt < 4; ++nt)
      sm[nt] = sacc[nt] + *(const f32x4*)(madd + kvh * 64 + 16 * nt + 4 * lg);
    float q4[4];
#pragma unroll
    for (int nt = 0; nt < 4; ++nt)
      q4[nt] = fmaxf(fmaxf(sm[nt][0], sm[nt][1]), fmaxf(sm[nt][2], sm[nt][3]));
    float tm = fmaxf(fmaxf(q4[0], q4[1]), fmaxf(q4[2], q4[3]));
    tm = fmaxf(tm, __shfl_xor(tm, 16));
    tm = fmaxf(tm, __shfl_xor(tm, 32));
    const float mn = fmaxf(m_r, tm);
    const float scale = __expf(m_r - mn);
    m_r = mn;
    float pv[4][4];
#pragma unroll
    for (int nt = 0; nt < 4; ++nt)
#pragma unroll
      for (int r = 0; r < 4; ++r) pv[nt][r] = __expf(sm[nt][r] - mn);
    float rs = ((pv[0][0] + pv[0][1]) + (pv[0][2] + pv[0][3])) +
               ((pv[1][0] + pv[1][1]) + (pv[1][2] + pv[1][3])) +
               ((pv[2][0] + pv[2][1]) + (pv[2][2] + pv[2][3])) +
               ((pv[3][0] + pv[3][1]) + (pv[3][2] + pv[3][3]));
    rs += __shfl_xor(rs, 16);
    rs += __shfl_xor(rs, 32);
    l_r = l_r * scale + rs;
#pragma unroll
    for (int nt = 0; nt < 4; ++nt)
      *(f16x4*)(Pl + w * 1152 + l15 * VST + 16 * nt + 4 * lg) =
          (f16x4){(f16)pv[nt][0], (f16)pv[nt][1], (f16)pv[nt][2], (f16)pv[nt][3]};
    f32x4 scv;
#pragma unroll
    for (int r = 0; r < 4; ++r) scv[r] = __shfl(scale, 4 * lg + r);
#pragma unroll
    for (int dt = 0; dt < 8; ++dt) acco[dt] *= scv;

    // ---- PV: A = P (row=qrow=l15, k=64 keys), B = Vt (n = d = l15+16dt) ----
    f16x8 pa0 = *(const f16x8*)(Pl + w * 1152 + l15 * VST + 8 * lg);
    f16x8 pa1 = *(const f16x8*)(Pl + w * 1152 + l15 * VST + 32 + 8 * lg);
#pragma unroll
    for (int dt = 0; dt < 8; ++dt) {
      f16x8 vf0 = *(const f16x8*)(Vt + kvh * 9216 + (l15 + 16 * dt) * VST + 8 * lg);
      f16x8 vf1 = *(const f16x8*)(Vt + kvh * 9216 + (l15 + 16 * dt) * VST + 32 + 8 * lg);
      acco[dt] = __builtin_amdgcn_mfma_f32_16x16x32_f16(pa0, vf0, acco[dt], 0, 0, 0);
      acco[dt] = __builtin_amdgcn_mfma_f32_16x16x32_f16(pa1, vf1, acco[dt], 0, 0, 0);
    }
    __syncthreads();
  }

  // ---- epilogue: merge the two kv-halves (LDS overlay safe past final barrier) ----
  if (kvh == 1) {
#pragma unroll
    for (int r = 0; r < 4; ++r) {
      const int row = 4 * lg + r;
#pragma unroll
      for (int dt = 0; dt < 8; ++dt)
        mrg[rowgrp * 2112 + row * 132 + l15 + 16 * dt] = acco[dt][r];
    }
    if (lg == 0) {
      mlb[rowgrp * 32 + l15 * 2]     = m_r;
      mlb[rowgrp * 32 + l15 * 2 + 1] = l_r;
    }
  }
  __syncthreads();
  if (kvh == 0) {
    float m1[4], l1[4];
#pragma unroll
    for (int r = 0; r < 4; ++r) {
      m1[r] = __shfl(m_r, 4 * lg + r);
      l1[r] = __shfl(l_r, 4 * lg + r);
    }
#pragma unroll
    for (int r = 0; r < 4; ++r) {
      const int row = 4 * lg + r;
      const float m2 = mlb[rowgrp * 32 + row * 2];
      const float l2 = mlb[rowgrp * 32 + row * 2 + 1];
      const float mm = fmaxf(m1[r], m2);
      const float e1 = __expf(m1[r] - mm);
      const float e2 = __expf(m2 - mm);
      const float inv = 1.0f / (l1[r] * e1 + l2 * e2);
      float* op = O + ((size_t)b * S_ + q0 + 16 * rowgrp + row) * D_ + l15;
#pragma unroll
      for (int dt = 0; dt < 8; ++dt)
        op[16 * dt] = (acco[dt][r] * e1 + mrg[rowgrp * 2112 + row * 132 + l15 + 16 * dt] * e2) * inv;
    }
  }
}

extern "C" void kernel_launch(void* const* d_in, const int* in_sizes, int n_in,
                              void* d_out, int out_size, void* d_ws, size_t ws_size,
                              hipStream_t stream) {
  const float* q = (const float*)d_in[0];
  const float* k = (const float*)d_in[1];
  const float* v = (const float*)d_in[2];
  const void*  m = d_in[3];
  float* o = (float*)d_out;
  dim3 grid((S_ / QBLK) * B_);   // 256, 1D: bid%8 = batch -> XCD-local K/V
  dim3 block(512);
  attn_fwd<<<grid, block, 0, stream>>>(q, k, v, m, o);
}

// Round 16
// 134.589 us; speedup vs baseline: 1.1249x; 1.1249x over previous
//
#include <hip/hip_runtime.h>
#include <hip/hip_bf16.h>
#include <stdint.h>

#define B_ 8
#define S_ 2048
#define D_ 128
#define QBLK 64
#define KVB 32
#define SHALF 1024
#define NIT (SHALF / KVB)   // 32
#define VST 40              // padded f16 stride for V^T / P tiles

typedef _Float16 f16;
typedef f16 f16x8 __attribute__((ext_vector_type(8)));
typedef f16 f16x4 __attribute__((ext_vector_type(4)));
typedef f16 f16x2 __attribute__((ext_vector_type(2)));
typedef float f32x4 __attribute__((ext_vector_type(4)));

// 512 threads = 8 waves: rowgrp = w&3 (16 q-rows each), kvh = w>>2 (key half).
// Two barriers per iteration (PROVEN race-free r11; r14's 1-barrier dbuf raced).
// LDS: [0,16384) Klds 2x[32][128] f16 swizzled | [16384,36864) Vt 2x[128][VST] f16
//      [36864,47104) Pl 8x[16][VST] f16 | [47104,47360) madd 64 f32
// epilogue overlay (all staging reads complete): mrg 4x[16][132] f32 @0,
//      mlb 4x[16][2] f32 @36864
__global__ __launch_bounds__(512, 2) void attn_fwd(const float* __restrict__ Q,
                                                   const float* __restrict__ K,
                                                   const float* __restrict__ V,
                                                   const void* __restrict__ Mp,
                                                   float* __restrict__ O) {
  const int t = threadIdx.x;
  const int bid = blockIdx.x;
  const int b = bid & 7;             // XCD-aware: batch == bid%8 (L2-local K/V, r13-proven)
  const int q0 = (bid >> 3) * QBLK;
  const int w = t >> 6, l = t & 63, l15 = l & 15, lg = l >> 4;
  const int rowgrp = w & 3, kvh = w >> 2;

  __shared__ alignas(16) char smem[47360];
  f16* Klds  = (f16*)smem;
  f16* Vt    = (f16*)(smem + 16384);
  f16* Pl    = (f16*)(smem + 36864);
  float* madd = (float*)(smem + 47104);
  float* mrg = (float*)smem;
  float* mlb = (float*)(smem + 36864);

  // ---- mask dtype detection (int32 / uint8-bool / float32), block-uniform ----
  const uint32_t* mw = (const uint32_t*)Mp;
  int oki = 1, okf = 1;
#pragma unroll
  for (int i = 0; i < 4; ++i) {
    uint32_t x = mw[t * 4 + i];
    oki &= (x <= 1u) ? 1 : 0;
    okf &= (x == 0u || x == 0x3f800000u) ? 1 : 0;
  }
  const int alli = __syncthreads_and(oki);
  const int allf = __syncthreads_and(okf);
  const int mode = alli ? 0 : (allf ? 2 : 1);
  const int*     mi32 = (const int*)Mp + b * S_;
  const uint8_t* mu8  = (const uint8_t*)Mp + b * S_;
  const float*   mf32 = (const float*)Mp + b * S_;

  // ---- Q fragments (B-operand of swapped QK): col n = l15 = qrow, k = lg*8+j+32kt ----
  f16x8 qf[4];
  {
    const int qrow = q0 + 16 * rowgrp + l15;
    const float* qp = Q + ((size_t)b * S_ + qrow) * D_ + lg * 8;
#pragma unroll
    for (int kt = 0; kt < 4; ++kt) {
      float4 a = *(const float4*)(qp + 32 * kt);
      float4 c = *(const float4*)(qp + 32 * kt + 4);
      qf[kt] = (f16x8){(f16)a.x, (f16)a.y, (f16)a.z, (f16)a.w,
                       (f16)c.x, (f16)c.y, (f16)c.z, (f16)c.w};
    }
  }

  f32x4 acco[8];
#pragma unroll
  for (int dt = 0; dt < 8; ++dt) acco[dt] = (f32x4){0.f, 0.f, 0.f, 0.f};
  float m_r = -1e30f, l_r = 0.f;  // per-lane state for qrow = l15 (replicated x4 lgs)

  // ---- staging geometry: 512 threads stage 64 keys (2 halves x 32) of K and V ----
  const float* Kb = K + (size_t)b * S_ * D_;
  const float* Vb = V + (size_t)b * S_ * D_;
  const int kc4 = (t & 31) * 4;   // K col
  const int kgr = t >> 5;         // K row group 0..15
  const int vc  = (t >> 4) * 4;   // V d base 0..124
  const int vkp = t & 15;         // V key-pair base

  float4 kreg[4], vreg[4];
  float mreg = 0.f;

#define LOADT(KV0)                                                                    \
  {                                                                                   \
    _Pragma("unroll") for (int p = 0; p < 4; ++p) {                                   \
      const int gr = kgr + 16 * p, half = gr >> 5, row = gr & 31;                     \
      kreg[p] = *(const float4*)(Kb + (size_t)(half * SHALF + (KV0) + row) * D_ + kc4); \
    }                                                                                 \
    _Pragma("unroll") for (int p = 0; p < 2; ++p) {                                   \
      const int kg = vkp + 16 * p, half = kg >> 4, kp = kg & 15;                      \
      const float* vp = Vb + (size_t)(half * SHALF + (KV0) + 2 * kp) * D_ + vc;       \
      vreg[2 * p]     = *(const float4*)vp;                                           \
      vreg[2 * p + 1] = *(const float4*)(vp + D_);                                    \
    }                                                                                 \
    if (t < 64) {                                                                     \
      const int gk = (t >> 5) * SHALF + (KV0) + (t & 31);                             \
      mreg = (mode == 0) ? (mi32[gk] ? 1.f : 0.f)                                     \
           : (mode == 1) ? (mu8[gk] ? 1.f : 0.f) : mf32[gk];                          \
    }                                                                                 \
  }

  LOADT(0);

  for (int it = 0; it < NIT; ++it) {
    const int kv0 = it * KVB;
    // ---- convert staged regs -> LDS ----
#pragma unroll
    for (int p = 0; p < 4; ++p) {
      const int gr = kgr + 16 * p, half = gr >> 5, row = gr & 31;
      const int idx = half * 4096 + ((row * 128 + kc4) ^ ((row & 7) << 3));
      float4 kv = kreg[p];
      *(f16x4*)(Klds + idx) = (f16x4){(f16)kv.x, (f16)kv.y, (f16)kv.z, (f16)kv.w};
    }
#pragma unroll
    for (int p = 0; p < 2; ++p) {
      const int kg = vkp + 16 * p, half = kg >> 4, kp = kg & 15;
      float4 v0 = vreg[2 * p], v1 = vreg[2 * p + 1];
#pragma unroll
      for (int i = 0; i < 4; ++i)
        *(f16x2*)(Vt + half * 5120 + (vc + i) * VST + 2 * kp) =
            (f16x2){(f16)(&v0.x)[i], (f16)(&v1.x)[i]};
    }
    if (t < 64) madd[t] = (mreg != 0.f) ? -1e30f : 0.f;
    __syncthreads();

    // ---- prefetch next tile (hides under QK/softmax/PV) ----
    if (it + 1 < NIT) LOADT(kv0 + KVB);

    // ---- swapped QK^T: sacc[nt][r] = S[key=16nt+4lg+r][qrow=l15] ----
    f32x4 sacc0 = (f32x4){0.f, 0.f, 0.f, 0.f};
    f32x4 sacc1 = (f32x4){0.f, 0.f, 0.f, 0.f};
#pragma unroll
    for (int kt = 0; kt < 4; ++kt) {
      const int col = lg * 8 + 32 * kt, swz = (l15 & 7) << 3;
      f16x8 kf0 = *(const f16x8*)(Klds + kvh * 4096 + ((l15 * 128 + col) ^ swz));
      f16x8 kf1 = *(const f16x8*)(Klds + kvh * 4096 + (((l15 + 16) * 128 + col) ^ swz));
      sacc0 = __builtin_amdgcn_mfma_f32_16x16x32_f16(kf0, qf[kt], sacc0, 0, 0, 0);
      sacc1 = __builtin_amdgcn_mfma_f32_16x16x32_f16(kf1, qf[kt], sacc1, 0, 0, 0);
    }

    // ---- lane-local softmax (qrow=l15): additive mask, 2-shuffle reductions ----
    f32x4 ma0 = *(const f32x4*)(madd + kvh * 32 + 4 * lg);
    f32x4 ma1 = *(const f32x4*)(madd + kvh * 32 + 16 + 4 * lg);
    f32x4 s0 = sacc0 + ma0, s1 = sacc1 + ma1;
    float tm = fmaxf(fmaxf(fmaxf(s0[0], s0[1]), fmaxf(s0[2], s0[3])),
                     fmaxf(fmaxf(s1[0], s1[1]), fmaxf(s1[2], s1[3])));
    tm = fmaxf(tm, __shfl_xor(tm, 16));
    tm = fmaxf(tm, __shfl_xor(tm, 32));
    const float mn = fmaxf(m_r, tm);
    const float scale = __expf(m_r - mn);
    m_r = mn;
    float p0[4], p1[4];
#pragma unroll
    for (int r = 0; r < 4; ++r) { p0[r] = __expf(s0[r] - mn); p1[r] = __expf(s1[r] - mn); }
    float rs = (p0[0] + p0[1]) + (p0[2] + p0[3]) + (p1[0] + p1[1]) + (p1[2] + p1[3]);
    rs += __shfl_xor(rs, 16);
    rs += __shfl_xor(rs, 32);
    l_r = l_r * scale + rs;
    // P write: Pl[w][qrow=l15][key]
    *(f16x4*)(Pl + w * 640 + l15 * VST + 4 * lg) =
        (f16x4){(f16)p0[0], (f16)p0[1], (f16)p0[2], (f16)p0[3]};
    *(f16x4*)(Pl + w * 640 + l15 * VST + 16 + 4 * lg) =
        (f16x4){(f16)p1[0], (f16)p1[1], (f16)p1[2], (f16)p1[3]};
    // redistribute scale to acco layout (qrow = 4lg+r)
    f32x4 scv;
#pragma unroll
    for (int r = 0; r < 4; ++r) scv[r] = __shfl(scale, 4 * lg + r);
#pragma unroll
    for (int dt = 0; dt < 8; ++dt) acco[dt] *= scv;

    // ---- PV: A=P (row=qrow=l15, k=keys 8lg..8lg+7), B=Vt (n=d=l15+16dt) ----
    f16x8 pa = *(const f16x8*)(Pl + w * 640 + l15 * VST + lg * 8);
#pragma unroll
    for (int dt = 0; dt < 8; ++dt) {
      f16x8 vf = *(const f16x8*)(Vt + kvh * 5120 + (l15 + 16 * dt) * VST + lg * 8);
      acco[dt] = __builtin_amdgcn_mfma_f32_16x16x32_f16(pa, vf, acco[dt], 0, 0, 0);
    }
    __syncthreads();
  }

  // ---- epilogue: merge the two kv-halves (LDS overlay safe past final barrier) ----
  if (kvh == 1) {
#pragma unroll
    for (int r = 0; r < 4; ++r) {
      const int row = 4 * lg + r;
#pragma unroll
      for (int dt = 0; dt < 8; ++dt)
        mrg[rowgrp * 2112 + row * 132 + l15 + 16 * dt] = acco[dt][r];
    }
    if (lg == 0) {
      mlb[rowgrp * 32 + l15 * 2]     = m_r;
      mlb[rowgrp * 32 + l15 * 2 + 1] = l_r;
    }
  }
  __syncthreads();
  if (kvh == 0) {
    float m1[4], l1[4];
#pragma unroll
    for (int r = 0; r < 4; ++r) {
      m1[r] = __shfl(m_r, 4 * lg + r);
      l1[r] = __shfl(l_r, 4 * lg + r);
    }
#pragma unroll
    for (int r = 0; r < 4; ++r) {
      const int row = 4 * lg + r;
      const float m2 = mlb[rowgrp * 32 + row * 2];
      const float l2 = mlb[rowgrp * 32 + row * 2 + 1];
      const float mm = fmaxf(m1[r], m2);
      const float e1 = __expf(m1[r] - mm);
      const float e2 = __expf(m2 - mm);
      const float inv = 1.0f / (l1[r] * e1 + l2 * e2);
      float* op = O + ((size_t)b * S_ + q0 + 16 * rowgrp + row) * D_ + l15;
#pragma unroll
      for (int dt = 0; dt < 8; ++dt)
        op[16 * dt] = (acco[dt][r] * e1 + mrg[rowgrp * 2112 + row * 132 + l15 + 16 * dt] * e2) * inv;
    }
  }
}

extern "C" void kernel_launch(void* const* d_in, const int* in_sizes, int n_in,
                              void* d_out, int out_size, void* d_ws, size_t ws_size,
                              hipStream_t stream) {
  const float* q = (const float*)d_in[0];
  const float* k = (const float*)d_in[1];
  const float* v = (const float*)d_in[2];
  const void*  m = d_in[3];
  float* o = (float*)d_out;
  dim3 grid((S_ / QBLK) * B_);   // 256, 1D: bid%8 = batch -> XCD-local K/V
  dim3 block(512);
  attn_fwd<<<grid, block, 0, stream>>>(q, k, v, m, o);
}